// Round 1
// baseline (83.249 us; speedup 1.0000x reference)
//
#include <hip/hip_runtime.h>

#define N_FFT 1024
#define SPLIT0 513
// Swizzle to break LDS bank conflicts: pad by 1 word every 32.
#define PAD(a) ((a) + ((a) >> 5))

// Radix-4 DIF butterfly with twiddles on outputs 1..3.
// Inputs a,b,c,d = src[t], src[t+256], src[t+512], src[t+768].
__device__ __forceinline__ void bfly4(
    float ar, float ai, float br, float bi,
    float cr, float ci, float dr, float di,
    float w1r, float w1i, float w2r, float w2i, float w3r, float w3i,
    float& y0r, float& y0i, float& y1r, float& y1i,
    float& y2r, float& y2i, float& y3r, float& y3i)
{
    float t0r = ar + cr, t0i = ai + ci;
    float t1r = ar - cr, t1i = ai - ci;
    float t2r = br + dr, t2i = bi + di;
    float t3r = br - dr, t3i = bi - di;
    float u0r = t0r + t2r, u0i = t0i + t2i;
    float u1r = t1r + t3i, u1i = t1i - t3r;   // t1 + (-i)*t3
    float u2r = t0r - t2r, u2i = t0i - t2i;
    float u3r = t1r - t3i, u3i = t1i + t3r;   // t1 - (-i)*t3
    y0r = u0r;                 y0i = u0i;
    y1r = u1r * w1r - u1i * w1i;  y1i = u1r * w1i + u1i * w1r;
    y2r = u2r * w2r - u2i * w2i;  y2i = u2r * w2i + u2i * w2r;
    y3r = u3r * w3r - u3i * w3i;  y3i = u3r * w3i + u3i * w3r;
}

__device__ __forceinline__ void cmul(float ar, float ai, float br, float bi,
                                     float& cr, float& ci) {
    // NOTE: outputs must not alias inputs at call sites.
    cr = ar * br - ai * bi;
    ci = ar * bi + ai * br;
}

// One WAVE (64 lanes) per pair of rows: z = row0 + i*row1, 1024-pt complex FFT.
// Lane l holds z[w] = X[l + 64w], w=0..15. Passes (0,1) and (2,3) are fused in
// registers (radix-16); only two LDS exchanges + the final untangle pass.
// Single-wave workgroup => s_barrier elided, no cross-wave sync at all.
__global__ __launch_bounds__(64) void rfft1024_wave(const float* __restrict__ x,
                                                    float* __restrict__ out,
                                                    int nrows) {
    __shared__ float sre[1056];   // PAD(1023)=1054 < 1056
    __shared__ float sim[1056];

    const int l = threadIdx.x;            // lane 0..63
    const int pair = blockIdx.x;
    const float* __restrict__ r0 = x + (size_t)(2 * pair) * N_FFT;
    const float* __restrict__ r1 = r0 + N_FFT;

    // ---- load: z[w] = X[l + 64w]; coalesced dword loads (base+imm offsets) ----
    float zr[16], zi[16];
#pragma unroll
    for (int w = 0; w < 16; ++w) {
        zr[w] = r0[l + 64 * w];
        zi[w] = r1[l + 64 * w];
    }

    // exp(-2*pi*i*s/16), s=0..3 (compile-time constants after unroll)
    const float C16R[4] = {1.0f, 0.92387953251128675613f,
                           0.70710678118654752440f, 0.38268343236508977173f};
    const float C16I[4] = {0.0f, -0.38268343236508977173f,
                           -0.70710678118654752440f, -0.92387953251128675613f};
    const float TWO_PI = 6.28318530717958647692f;

    // Base twiddle W(l) = exp(-2*pi*i*l/1024): the ONLY per-lane sincos (x2 total).
    float wlr, wli;
    { float s, c; __sincosf(-TWO_PI * (float)l * (1.0f / 1024.0f), &s, &c); wlr = c; wli = s; }

    // ---- fused passes 0 (m=1) and 1 (m=4), all in registers ----
    // Pass 0, virtual thread u = l + 64s: twiddle W(u) = W(l)*C16(s).
    float o0r[4][4], o0i[4][4];
#pragma unroll
    for (int s = 0; s < 4; ++s) {
        float w1r, w1i; cmul(wlr, wli, C16R[s], C16I[s], w1r, w1i);
        float w2r, w2i; cmul(w1r, w1i, w1r, w1i, w2r, w2i);
        float w3r, w3i; cmul(w1r, w1i, w2r, w2i, w3r, w3i);
        bfly4(zr[s], zi[s], zr[s + 4], zi[s + 4], zr[s + 8], zi[s + 8], zr[s + 12], zi[s + 12],
              w1r, w1i, w2r, w2i, w3r, w3i,
              o0r[s][0], o0i[s][0], o0r[s][1], o0i[s][1],
              o0r[s][2], o0i[s][2], o0r[s][3], o0i[s][3]);
    }
    // Pass 1, virtual thread u' = 4l + p: jm = 4l, twiddle W(4l) = W(l)^4, same for all p.
    float v1r[4][4], v1i[4][4];
    {
        float a2r, a2i; cmul(wlr, wli, wlr, wli, a2r, a2i);
        float w1r, w1i; cmul(a2r, a2i, a2r, a2i, w1r, w1i);     // W(l)^4
        float w2r, w2i; cmul(w1r, w1i, w1r, w1i, w2r, w2i);
        float w3r, w3i; cmul(w1r, w1i, w2r, w2i, w3r, w3i);
#pragma unroll
        for (int p = 0; p < 4; ++p) {
            bfly4(o0r[0][p], o0i[0][p], o0r[1][p], o0i[1][p],
                  o0r[2][p], o0i[2][p], o0r[3][p], o0i[3][p],
                  w1r, w1i, w2r, w2i, w3r, w3i,
                  v1r[p][0], v1i[p][0], v1r[p][1], v1i[p][1],
                  v1r[p][2], v1i[p][2], v1r[p][3], v1i[p][3]);
        }
    }

    // ---- exchange #1: write dst1[16l + 4r + p], read z[w] = dst1[l + 64w] ----
    // PAD(16l+idx) = 16l + (l>>1) + idx : stride-16 writes hit each bank exactly 2x (free).
#pragma unroll
    for (int p = 0; p < 4; ++p)
#pragma unroll
        for (int r = 0; r < 4; ++r) {
            int a = 16 * l + 4 * r + p;
            sre[PAD(a)] = v1r[p][r];
            sim[PAD(a)] = v1i[p][r];
        }
    __syncthreads();   // single-wave WG: compiles to waitcnt ordering only
#pragma unroll
    for (int w = 0; w < 16; ++w) {
        int a = l + 64 * w;
        zr[w] = sre[PAD(a)];
        zi[w] = sim[PAD(a)];
    }
    __syncthreads();

    // ---- fused passes 2 (m=16) and 3 (m=64), in registers ----
    const int k = l & 15, j0 = l >> 4;
    // D = exp(-2*pi*i*j0/64)
    float djr, dji;
    { float s, c; __sincosf(-TWO_PI * (float)j0 * (1.0f / 64.0f), &s, &c); djr = c; dji = s; }

    // Pass 2, virtual u = l + 64s: jm = 16*j0 + 64s, twiddle = D * C16(s).
    float o2r[4][4], o2i[4][4];
#pragma unroll
    for (int s = 0; s < 4; ++s) {
        float w1r, w1i; cmul(djr, dji, C16R[s], C16I[s], w1r, w1i);
        float w2r, w2i; cmul(w1r, w1i, w1r, w1i, w2r, w2i);
        float w3r, w3i; cmul(w1r, w1i, w2r, w2i, w3r, w3i);
        bfly4(zr[s], zi[s], zr[s + 4], zi[s + 4], zr[s + 8], zi[s + 8], zr[s + 12], zi[s + 12],
              w1r, w1i, w2r, w2i, w3r, w3i,
              o2r[s][0], o2i[s][0], o2r[s][1], o2i[s][1],
              o2r[s][2], o2i[s][2], o2r[s][3], o2i[s][3]);
    }
    // Pass 3, virtual u' = 64*j0 + 16p + k: jm = 64*j0, twiddle = D^4, same for all p.
    float v3r[4][4], v3i[4][4];
    {
        float b2r, b2i; cmul(djr, dji, djr, dji, b2r, b2i);
        float e1r, e1i; cmul(b2r, b2i, b2r, b2i, e1r, e1i);     // D^4 = exp(-2*pi*i*j0/16)
        float e2r, e2i; cmul(e1r, e1i, e1r, e1i, e2r, e2i);
        float e3r, e3i; cmul(e1r, e1i, e2r, e2i, e3r, e3i);
#pragma unroll
        for (int p = 0; p < 4; ++p) {
            bfly4(o2r[0][p], o2i[0][p], o2r[1][p], o2i[1][p],
                  o2r[2][p], o2i[2][p], o2r[3][p], o2i[3][p],
                  e1r, e1i, e2r, e2i, e3r, e3i,
                  v3r[p][0], v3i[p][0], v3r[p][1], v3i[p][1],
                  v3r[p][2], v3i[p][2], v3r[p][3], v3i[p][3]);
        }
    }

    // ---- exchange #2: write dst3[256*j0 + 64r + 16p + k], read z[w] = dst3[l + 64w] ----
#pragma unroll
    for (int p = 0; p < 4; ++p)
#pragma unroll
        for (int r = 0; r < 4; ++r) {
            int a = 256 * j0 + 64 * r + 16 * p + k;
            sre[PAD(a)] = v3r[p][r];
            sim[PAD(a)] = v3i[p][r];
        }
    __syncthreads();
#pragma unroll
    for (int w = 0; w < 16; ++w) {
        int a = l + 64 * w;
        zr[w] = sre[PAD(a)];
        zi[w] = sim[PAD(a)];
    }
    __syncthreads();

    // ---- pass 4 (m=256): no twiddles; write F[l + 64s + 256r] back to LDS ----
#pragma unroll
    for (int s = 0; s < 4; ++s) {
        float ar = zr[s],      ai = zi[s];
        float br = zr[s + 4],  bi = zi[s + 4];
        float cr = zr[s + 8],  ci = zi[s + 8];
        float dr = zr[s + 12], di = zi[s + 12];
        float t0r = ar + cr, t0i = ai + ci;
        float t1r = ar - cr, t1i = ai - ci;
        float t2r = br + dr, t2i = bi + di;
        float t3r = br - dr, t3i = bi - di;
        float y0r = t0r + t2r, y0i = t0i + t2i;
        float y1r = t1r + t3i, y1i = t1i - t3r;
        float y2r = t0r - t2r, y2i = t0i - t2i;
        float y3r = t1r - t3i, y3i = t1i + t3r;
        int a0 = l + 64 * s;
        sre[PAD(a0)]        = y0r;  sim[PAD(a0)]        = y0i;
        sre[PAD(a0 + 256)]  = y1r;  sim[PAD(a0 + 256)]  = y1i;
        sre[PAD(a0 + 512)]  = y2r;  sim[PAD(a0 + 512)]  = y2i;
        sre[PAD(a0 + 768)]  = y3r;  sim[PAD(a0 + 768)]  = y3i;
    }
    __syncthreads();

    // ---- untangle the two real spectra and store ----
    // X0[k] = (Z[k]+conj(Z[N-k]))/2 ; X1[k] = -i/2*(Z[k]-conj(Z[N-k])).
    const size_t row0 = (size_t)(2 * pair);
    float* __restrict__ outr = out;
    float* __restrict__ outi = out + (size_t)nrows * SPLIT0;

#pragma unroll
    for (int w = 0; w < 8; ++w) {
        int kk = l + 64 * w;                       // 0..511
        float a_r = sre[PAD(kk)], a_i = sim[PAD(kk)];
        int km = (N_FFT - kk) & (N_FFT - 1);
        float m_r = sre[PAD(km)], m_i = sim[PAD(km)];
        float X0r = 0.5f * (a_r + m_r), X0i = 0.5f * (a_i - m_i);
        float X1r = 0.5f * (a_i + m_i), X1i = 0.5f * (m_r - a_r);
        outr[row0 * SPLIT0 + kk]       = X0r;
        outi[row0 * SPLIT0 + kk]       = X0i;
        outr[(row0 + 1) * SPLIT0 + kk] = X1r;
        outi[(row0 + 1) * SPLIT0 + kk] = X1i;
    }
    if (l == 0) {
        // k = 512 (Nyquist): Z[512] = X0[512] + i*X1[512], both real.
        float a_r = sre[PAD(512)], a_i = sim[PAD(512)];
        outr[row0 * SPLIT0 + 512]       = a_r;
        outi[row0 * SPLIT0 + 512]       = 0.0f;
        outr[(row0 + 1) * SPLIT0 + 512] = a_i;
        outi[(row0 + 1) * SPLIT0 + 512] = 0.0f;
    }
}

extern "C" void kernel_launch(void* const* d_in, const int* in_sizes, int n_in,
                              void* d_out, int out_size, void* d_ws, size_t ws_size,
                              hipStream_t stream) {
    const float* x = (const float*)d_in[0];
    float* out = (float*)d_out;
    const int nrows = in_sizes[0] / N_FFT;  // 8192
    rfft1024_wave<<<nrows / 2, 64, 0, stream>>>(x, out, nrows);
}